// Round 6
// baseline (263.959 us; speedup 1.0000x reference)
//
#include <hip/hip_runtime.h>

// Problem constants
#define N 8
#define C 64
#define H 256
#define W 256
#define G 8
#define CG 8            // C/G
#define KK 9            // 3x3
#define HW (H*W)        // 65536

// native clang vector type for nontemporal builtins (HIP_vector_type is invalid there)
typedef float nfloat4 __attribute__((ext_vector_type(4)));

// ---------------------------------------------------------------------------
// Kernel 1: global average pool per (n,c).  One block per (n,c), 1024 threads,
// float4 loads, wave-shuffle reduce.  512 blocks -> 2 blocks/CU, 32 waves/CU.
// ---------------------------------------------------------------------------
__global__ __launch_bounds__(1024) void gap_kernel(const float* __restrict__ x,
                                                   float* __restrict__ gap) {
    const int nc = blockIdx.x;                     // 0..511
    const float4* x4 = (const float4*)(x + (size_t)nc * HW);
    float s = 0.f;
    #pragma unroll 8
    for (int i = threadIdx.x; i < HW / 4; i += 1024) {
        float4 v = x4[i];
        s += (v.x + v.y) + (v.z + v.w);
    }
    #pragma unroll
    for (int off = 32; off > 0; off >>= 1)
        s += __shfl_down(s, off, 64);
    __shared__ float red[16];
    const int wave = threadIdx.x >> 6;
    const int lane = threadIdx.x & 63;
    if (lane == 0) red[wave] = s;
    __syncthreads();
    if (threadIdx.x == 0) {
        float t = 0.f;
        #pragma unroll
        for (int wv = 0; wv < 16; ++wv) t += red[wv];
        gap[nc] = t * (1.0f / (float)HW);
    }
}

// ---------------------------------------------------------------------------
// Kernel 2: filt[n, o] = tanh( dot(gap[n,:], conv_w[o,:]) ), 576 outputs.
// ---------------------------------------------------------------------------
__global__ __launch_bounds__(256) void filt_kernel(const float* __restrict__ gap,
                                                   const float* __restrict__ conv_w,
                                                   float* __restrict__ filt) {
    const int idx = blockIdx.x * 256 + threadIdx.x;
    if (idx >= N * G * KK) return;
    const int n = idx / (G * KK);
    const int o = idx - n * (G * KK);
    const float* gp = gap + n * C;
    const float* wp = conv_w + o * C;
    float s = 0.f;
    #pragma unroll
    for (int c = 0; c < C; ++c) s += gp[c] * wp[c];
    filt[idx] = tanhf(s);
}

// ---------------------------------------------------------------------------
// Kernel 3: dynamic 3x3 conv + residual, reflect padding.
// Block = 256 threads = 4 waves; wave = 64 lanes = one full row of float4.
// Each wave runs TWO independent 8-row strips concurrently (dual rolling
// windows) with the raw load separated from its shuffle-finish by one
// iteration: >=4 independent loads in flight per wave, 2 compute chains.
// Grid = N*C*(H/64) = 2048 blocks = 8 blocks/CU.
// ---------------------------------------------------------------------------
__device__ __forceinline__ float4 load_raw(const float* __restrict__ xc, int rr,
                                           int lane) {
    rr = (rr < 0) ? 1 : (rr >= H ? H - 2 : rr);    // reflect (exclude-edge)
    return *(const float4*)(xc + (size_t)rr * W + lane * 4);
}

__device__ __forceinline__ void finish_row(int lane, const float4& v,
                                           float& l, float& r) {
    const float lu = __shfl_up(v.w, 1, 64);
    const float rd = __shfl_down(v.x, 1, 64);
    l = (lane == 0) ? v.y : lu;                    // col -1 -> col 1
    r = (lane == 63) ? v.z : rd;                   // col W -> col W-2
}

__global__ __launch_bounds__(256) void dynconv_kernel(const float* __restrict__ x,
                                                      const float* __restrict__ filt,
                                                      float* __restrict__ out) {
    const int bid = blockIdx.x;                    // 0..2047
    const int rb = bid & 3;                        // which 64-row chunk
    const int nc = bid >> 2;                       // n*C + c
    const int n = nc >> 6;
    const int c = nc & (C - 1);
    const int g = c >> 3;

    const float* f = filt + ((size_t)n * G + g) * KK;
    const float f00 = f[0], f01 = f[1], f02 = f[2];
    const float f10 = f[3], f11 = f[4], f12 = f[5];
    const float f20 = f[6], f21 = f[7], f22 = f[8];

    const int wave = threadIdx.x >> 6;
    const int lane = threadIdx.x & 63;
    const int s0 = rb * 64 + wave * 16;            // strip 0: rows [s0, s0+8)
    const int s1 = s0 + 8;                         // strip 1: rows [s1, s1+8)

    const float* xc = x + (size_t)nc * HW;
    float* oc = out + (size_t)nc * HW;

    // --- pipeline prologue: 6 independent loads in flight
    float4 r0a = load_raw(xc, s0 - 1, lane);
    float4 r0b = load_raw(xc, s0,     lane);
    float4 r0c = load_raw(xc, s0 + 1, lane);
    float4 r1a = load_raw(xc, s1 - 1, lane);
    float4 r1b = load_raw(xc, s1,     lane);
    float4 r1c = load_raw(xc, s1 + 1, lane);

    float4 p0 = r0a, c0 = r0b, raw0 = r0c;
    float4 p1 = r1a, c1 = r1b, raw1 = r1c;
    float p0l, p0r, c0l, c0r, p1l, p1r, c1l, c1r;
    finish_row(lane, p0, p0l, p0r);
    finish_row(lane, c0, c0l, c0r);
    finish_row(lane, p1, p1l, p1r);
    finish_row(lane, c1, c1l, c1r);

    #pragma unroll 4
    for (int i = 0; i < 8; ++i) {
        // prefetch row i+2 of each strip (2 loads issued before any consume)
        float4 pre0 = load_raw(xc, s0 + i + 2, lane);
        float4 pre1 = load_raw(xc, s1 + i + 2, lane);

        // finish row i+1 (loaded last iteration)
        float4 n0 = raw0, n1 = raw1;
        float n0l, n0r, n1l, n1r;
        finish_row(lane, n0, n0l, n0r);
        finish_row(lane, n1, n1l, n1r);

        // compute + store strip 0, row s0+i
        {
            const float am[6] = {p0l, p0.x, p0.y, p0.z, p0.w, p0r};
            const float bm[6] = {c0l, c0.x, c0.y, c0.z, c0.w, c0r};
            const float cm[6] = {n0l, n0.x, n0.y, n0.z, n0.w, n0r};
            nfloat4 o;
            #pragma unroll
            for (int k = 0; k < 4; ++k) {
                float acc = bm[k + 1];
                acc += f00 * am[k] + f01 * am[k + 1] + f02 * am[k + 2];
                acc += f10 * bm[k] + f11 * bm[k + 1] + f12 * bm[k + 2];
                acc += f20 * cm[k] + f21 * cm[k + 1] + f22 * cm[k + 2];
                o[k] = acc;
            }
            __builtin_nontemporal_store(o, (nfloat4*)(oc + (size_t)(s0 + i) * W + lane * 4));
        }
        // compute + store strip 1, row s1+i
        {
            const float am[6] = {p1l, p1.x, p1.y, p1.z, p1.w, p1r};
            const float bm[6] = {c1l, c1.x, c1.y, c1.z, c1.w, c1r};
            const float cm[6] = {n1l, n1.x, n1.y, n1.z, n1.w, n1r};
            nfloat4 o;
            #pragma unroll
            for (int k = 0; k < 4; ++k) {
                float acc = bm[k + 1];
                acc += f00 * am[k] + f01 * am[k + 1] + f02 * am[k + 2];
                acc += f10 * bm[k] + f11 * bm[k + 1] + f12 * bm[k + 2];
                acc += f20 * cm[k] + f21 * cm[k + 1] + f22 * cm[k + 2];
                o[k] = acc;
            }
            __builtin_nontemporal_store(o, (nfloat4*)(oc + (size_t)(s1 + i) * W + lane * 4));
        }

        // rotate windows
        p0 = c0; p0l = c0l; p0r = c0r;
        c0 = n0; c0l = n0l; c0r = n0r;
        raw0 = pre0;
        p1 = c1; p1l = c1l; p1r = c1r;
        c1 = n1; c1l = n1l; c1r = n1r;
        raw1 = pre1;
    }
}

// ---------------------------------------------------------------------------
extern "C" void kernel_launch(void* const* d_in, const int* in_sizes, int n_in,
                              void* d_out, int out_size, void* d_ws, size_t ws_size,
                              hipStream_t stream) {
    const float* x      = (const float*)d_in[0];
    const float* conv_w = (const float*)d_in[1];
    float* out = (float*)d_out;

    float* gap  = (float*)d_ws;                    // 512 floats
    float* filt = (float*)d_ws + 512;              // 576 floats

    gap_kernel<<<N * C, 1024, 0, stream>>>(x, gap);
    filt_kernel<<<(N * G * KK + 255) / 256, 256, 0, stream>>>(gap, conv_w, filt);
    dynconv_kernel<<<N * C * (H / 64), 256, 0, stream>>>(x, filt, out);
}